// Round 1
// baseline (201.154 us; speedup 1.0000x reference)
//
#include <hip/hip_runtime.h>

// LinearAttention: B=2, L=2048, D=1024, H=16, d=64.
// Pipeline: cvt(x,Wqkv,outw -> bf16) ; QKV GEMM (bf16 MFMA, bias, k*=1/8, out bf16)
//           ; per-chunk K^T V local sums ; chunk prefix (fp32 run -> bf16 transposed)
//           ; per-chunk attn: P=tril(QK^T), Y=PV+Q*S (all MFMA) ; out GEMM (bias, fp32 out)

#define DEV __device__ __forceinline__

typedef __attribute__((ext_vector_type(8))) short bf16x8;
typedef __attribute__((ext_vector_type(4))) float f32x4;

DEV ushort f2bf(float f) {
  union { float f; unsigned u; } v; v.f = f;
  unsigned r = v.u + 0x7fffu + ((v.u >> 16) & 1u);
  return (ushort)(r >> 16);
}
DEV float bf2f(unsigned b) {
  union { unsigned u; float f; } v; v.u = (b & 0xffffu) << 16;
  return v.f;
}
DEV void glds16(const ushort* g, ushort* l) {
  __builtin_amdgcn_global_load_lds(
      (const __attribute__((address_space(1))) unsigned int*)g,
      (__attribute__((address_space(3))) unsigned int*)l, 16, 0, 0);
}

__global__ __launch_bounds__(256) void cvt_bf16(const float* __restrict__ in,
                                                ushort* __restrict__ out, int n4) {
  int i = blockIdx.x * 256 + threadIdx.x;
  if (i >= n4) return;
  float4 v = ((const float4*)in)[i];
  ushort4 o;
  o.x = f2bf(v.x); o.y = f2bf(v.y); o.z = f2bf(v.z); o.w = f2bf(v.w);
  ((ushort4*)out)[i] = o;
}

// C = A[M,K] * Bw[N,K]^T + bias ; NT GEMM, m97-style 128x128x32 tiles.
template <bool OUT_BF16, bool KSCALE>
__global__ __launch_bounds__(256) void gemm_bt(const ushort* __restrict__ A,
                                               const ushort* __restrict__ Bw,
                                               const float* __restrict__ bias,
                                               void* __restrict__ Cout,
                                               int M, int N, int K) {
  __shared__ ushort As[128 * 32];
  __shared__ ushort Bs[128 * 32];
  const int t = threadIdx.x;
  const int wid = t >> 6, lane = t & 63;
  const int quad = lane >> 4, l16 = lane & 15;
  const int bm = blockIdx.y * 128, bn = blockIdx.x * 128;
  const int wm = (wid >> 1) * 64, wn = (wid & 1) * 64;

  f32x4 acc[4][4];
  const f32x4 z = {0.f, 0.f, 0.f, 0.f};
#pragma unroll
  for (int i = 0; i < 4; ++i)
#pragma unroll
    for (int j = 0; j < 4; ++j) acc[i][j] = z;

  const ushort* ag = A + (size_t)(bm + (t >> 2)) * K + ((t & 3) * 8);
  const ushort* bg = Bw + (size_t)(bn + (t >> 2)) * K + ((t & 3) * 8);
  ushort* asl = As + wid * 512;  // wave-uniform LDS base; HW scatters lane*16B
  ushort* bsl = Bs + wid * 512;
  const size_t rowskip = (size_t)64 * K;

  for (int k0 = 0; k0 < K; k0 += 32) {
    glds16(ag + k0, asl);
    glds16(ag + k0 + rowskip, asl + 2048);
    glds16(bg + k0, bsl);
    glds16(bg + k0 + rowskip, bsl + 2048);
    __syncthreads();
    bf16x8 af[4], bf[4];
#pragma unroll
    for (int i = 0; i < 4; ++i) {
      af[i] = *(const bf16x8*)(As + (wm + i * 16 + l16) * 32 + quad * 8);
      bf[i] = *(const bf16x8*)(Bs + (wn + i * 16 + l16) * 32 + quad * 8);
    }
#pragma unroll
    for (int i = 0; i < 4; ++i)
#pragma unroll
      for (int j = 0; j < 4; ++j)
        acc[i][j] = __builtin_amdgcn_mfma_f32_16x16x32_bf16(af[i], bf[j], acc[i][j], 0, 0, 0);
    __syncthreads();
  }

#pragma unroll
  for (int i = 0; i < 4; ++i)
#pragma unroll
    for (int j = 0; j < 4; ++j) {
      const int col = bn + wn + j * 16 + l16;
      const float bv = bias[col];
      float sc = 1.f;
      if (KSCALE) sc = ((col >> 10) == 1) ? 0.125f : 1.f;  // k block scaled AFTER bias
#pragma unroll
      for (int r = 0; r < 4; ++r) {
        const int row = bm + wm + i * 16 + quad * 4 + r;
        const float v = (acc[i][j][r] + bv) * sc;
        if (OUT_BF16)
          ((ushort*)Cout)[(size_t)row * N + col] = f2bf(v);
        else
          ((float*)Cout)[(size_t)row * N + col] = v;
      }
    }
}

// Per-(bh,chunk) local KV outer-product sums: mlocT[bh][c][e][f] = sum_s v[s][e]*k[s][f]
__global__ __launch_bounds__(256) void kv_local(const ushort* __restrict__ qkv,
                                                float* __restrict__ mlocT) {
  const int c = blockIdx.x, bh = blockIdx.y;
  const int b = bh >> 4, hd = bh & 15;
  const int t = threadIdx.x;
  __shared__ float kk[32 * 65];  // +1 pad: scalar-write bank spread
  __shared__ float vv[32 * 65];
  float s[16];
#pragma unroll
  for (int j = 0; j < 16; ++j) s[j] = 0.f;
  const int e = t >> 2, fb = (t & 3) * 16;
  const int step = t >> 3, el = (t & 7) * 8;
  for (int sb = 0; sb < 4; ++sb) {
    const ushort* kg = qkv + (size_t)(b * 2048 + c * 128 + sb * 32 + step) * 3072 + 1024 + hd * 64 + el;
    uint4 kr = *(const uint4*)kg;
    uint4 vr = *(const uint4*)(kg + 1024);
    float* kd = kk + step * 65 + el;
    float* vd = vv + step * 65 + el;
    kd[0] = bf2f(kr.x); kd[1] = bf2f(kr.x >> 16);
    kd[2] = bf2f(kr.y); kd[3] = bf2f(kr.y >> 16);
    kd[4] = bf2f(kr.z); kd[5] = bf2f(kr.z >> 16);
    kd[6] = bf2f(kr.w); kd[7] = bf2f(kr.w >> 16);
    vd[0] = bf2f(vr.x); vd[1] = bf2f(vr.x >> 16);
    vd[2] = bf2f(vr.y); vd[3] = bf2f(vr.y >> 16);
    vd[4] = bf2f(vr.z); vd[5] = bf2f(vr.z >> 16);
    vd[6] = bf2f(vr.w); vd[7] = bf2f(vr.w >> 16);
    __syncthreads();
    for (int l = 0; l < 32; ++l) {
      const float ve = vv[l * 65 + e];
      const float* krow = kk + l * 65 + fb;
#pragma unroll
      for (int j = 0; j < 16; ++j) s[j] += ve * krow[j];
    }
    __syncthreads();
  }
  float* out = mlocT + ((size_t)bh * 16 + c) * 4096 + e * 64 + fb;
#pragma unroll
  for (int j = 0; j < 16; ++j) out[j] = s[j];
}

// Exclusive prefix over chunks; fp32 running sum, bf16 output (already [e][f] layout).
__global__ __launch_bounds__(256) void kv_prefix(const float* __restrict__ mlocT,
                                                 ushort* __restrict__ statesT) {
  const int bh = blockIdx.x, t = threadIdx.x;
  float run[16];
#pragma unroll
  for (int j = 0; j < 16; ++j) run[j] = 0.f;
  for (int c = 0; c < 16; ++c) {
    const size_t base = ((size_t)bh * 16 + c) * 1024;  // float4 units
#pragma unroll
    for (int k = 0; k < 4; ++k) {
      const size_t idx = base + (size_t)k * 256 + t;
      ushort4 o;
      o.x = f2bf(run[k * 4 + 0]); o.y = f2bf(run[k * 4 + 1]);
      o.z = f2bf(run[k * 4 + 2]); o.w = f2bf(run[k * 4 + 3]);
      ((ushort4*)statesT)[idx] = o;
      const float4 m = ((const float4*)mlocT)[idx];
      run[k * 4 + 0] += m.x; run[k * 4 + 1] += m.y;
      run[k * 4 + 2] += m.z; run[k * 4 + 3] += m.w;
    }
  }
}

// Per-(bh,chunk): P = tril(Q K^T) ; Y = P V + Q S_prefix  (all bf16 MFMA, fp32 acc)
__global__ __launch_bounds__(256) void attn_chunk(const ushort* __restrict__ qkv,
                                                  const ushort* __restrict__ statesT,
                                                  ushort* __restrict__ yb) {
  const int c = blockIdx.x, bh = blockIdx.y;
  const int b = bh >> 4, hd = bh & 15;
  const int l0 = c * 128;
  const int t = threadIdx.x;
  const int wid = t >> 6, lane = t & 63;
  const int quad = lane >> 4, l16 = lane & 15;

  __shared__ ushort P[128 * 128];  // 32KB scores (bf16)
  __shared__ ushort U[128 * 128];  // 32KB union: phase1 {Qs,Ks} -> phase2 {vT,sT}
  ushort* Qs = U;
  ushort* Ks = U + 8192;
  ushort* vT = U;           // [e][s] 64x128
  ushort* sT = U + 8192;    // [e][f] 64x64

  {  // zero P (tiles above diagonal stay zero)
    uint4 zz; zz.x = zz.y = zz.z = zz.w = 0u;
    uint4* p4 = (uint4*)P;
#pragma unroll
    for (int i = 0; i < 8; ++i) p4[i * 256 + t] = zz;
  }
  {  // stage Q,K via global_load_lds (contiguous [row][64] tiles)
    const ushort* qg = qkv + (size_t)(b * 2048 + l0 + (t >> 3)) * 3072 + hd * 64 + ((t & 7) * 8);
    ushort* ql = Qs + wid * 512;
    ushort* kl = Ks + wid * 512;
#pragma unroll
    for (int h2 = 0; h2 < 4; ++h2) {
      glds16(qg + (size_t)h2 * 32 * 3072, ql + h2 * 2048);
      glds16(qg + (size_t)h2 * 32 * 3072 + 1024, kl + h2 * 2048);
    }
  }
  __syncthreads();

  // Q fragments held in registers across both phases (frees Qs for overlay)
  bf16x8 qf[2][2];
#pragma unroll
  for (int i = 0; i < 2; ++i)
#pragma unroll
    for (int kc = 0; kc < 2; ++kc)
      qf[i][kc] = *(const bf16x8*)(Qs + ((wid * 2 + i) * 16 + l16) * 64 + kc * 32 + quad * 8);

  const f32x4 z4 = {0.f, 0.f, 0.f, 0.f};
  f32x4 pacc[2][8];
#pragma unroll
  for (int i = 0; i < 2; ++i)
#pragma unroll
    for (int j = 0; j < 8; ++j) pacc[i][j] = z4;

#pragma unroll
  for (int i = 0; i < 2; ++i) {
    const int rt = wid * 2 + i;
#pragma unroll
    for (int tj = 0; tj < 8; ++tj) {
      if (tj <= rt) {  // skip fully-masked tiles (wave-uniform branch)
#pragma unroll
        for (int kc = 0; kc < 2; ++kc) {
          bf16x8 kfr = *(const bf16x8*)(Ks + (tj * 16 + l16) * 64 + kc * 32 + quad * 8);
          pacc[i][tj] = __builtin_amdgcn_mfma_f32_16x16x32_bf16(qf[i][kc], kfr, pacc[i][tj], 0, 0, 0);
        }
      }
    }
  }
  __syncthreads();

  // write masked P (C/D layout: row=quad*4+r, col=l16)
#pragma unroll
  for (int i = 0; i < 2; ++i) {
    const int rt = wid * 2 + i;
#pragma unroll
    for (int tj = 0; tj < 8; ++tj) {
      if (tj <= rt) {
#pragma unroll
        for (int r = 0; r < 4; ++r) {
          const int row = rt * 16 + quad * 4 + r;
          const int scol = tj * 16 + l16;
          const float v = (scol <= row) ? pacc[i][tj][r] : 0.f;
          P[row * 128 + scol] = f2bf(v);
        }
      }
    }
  }
  {  // stage V transposed: vT[e][s]
    const int sstep = t >> 1, eb = (t & 1) * 32;
    const ushort* vg = qkv + (size_t)(b * 2048 + l0 + sstep) * 3072 + 2048 + hd * 64 + eb;
    ushort tmp[32];
    *(uint4*)(tmp + 0)  = *(const uint4*)(vg + 0);
    *(uint4*)(tmp + 8)  = *(const uint4*)(vg + 8);
    *(uint4*)(tmp + 16) = *(const uint4*)(vg + 16);
    *(uint4*)(tmp + 24) = *(const uint4*)(vg + 24);
#pragma unroll
    for (int j = 0; j < 32; ++j) vT[(eb + j) * 128 + sstep] = tmp[j];
  }
  {  // stage S (already transposed [e][f] in global)
    const ushort* sg = statesT + ((size_t)bh * 16 + c) * 4096 + (size_t)t * 8;
    glds16(sg, sT + wid * 512);
    glds16(sg + 2048, sT + 2048 + wid * 512);
  }
  __syncthreads();

  f32x4 yacc[2][4];
#pragma unroll
  for (int i = 0; i < 2; ++i)
#pragma unroll
    for (int j = 0; j < 4; ++j) yacc[i][j] = z4;

#pragma unroll
  for (int i = 0; i < 2; ++i) {
    const int rt = wid * 2 + i;
    const int kcmax = rt >> 1;
#pragma unroll
    for (int kc = 0; kc < 4; ++kc) {
      if (kc <= kcmax) {  // P is zero beyond the diagonal: skip those K-chunks
        bf16x8 pf = *(const bf16x8*)(P + (rt * 16 + l16) * 128 + kc * 32 + quad * 8);
#pragma unroll
        for (int ct = 0; ct < 4; ++ct) {
          bf16x8 vf = *(const bf16x8*)(vT + (ct * 16 + l16) * 128 + kc * 32 + quad * 8);
          yacc[i][ct] = __builtin_amdgcn_mfma_f32_16x16x32_bf16(pf, vf, yacc[i][ct], 0, 0, 0);
        }
      }
    }
#pragma unroll
    for (int kc = 0; kc < 2; ++kc) {
#pragma unroll
      for (int ct = 0; ct < 4; ++ct) {
        bf16x8 sf = *(const bf16x8*)(sT + (ct * 16 + l16) * 64 + kc * 32 + quad * 8);
        yacc[i][ct] = __builtin_amdgcn_mfma_f32_16x16x32_bf16(qf[i][kc], sf, yacc[i][ct], 0, 0, 0);
      }
    }
  }

#pragma unroll
  for (int i = 0; i < 2; ++i) {
    const int rt = wid * 2 + i;
#pragma unroll
    for (int ct = 0; ct < 4; ++ct) {
#pragma unroll
      for (int r = 0; r < 4; ++r) {
        const int row = rt * 16 + quad * 4 + r;
        const int e = ct * 16 + l16;
        yb[(size_t)(b * 2048 + l0 + row) * 1024 + hd * 64 + e] = f2bf(yacc[i][ct][r]);
      }
    }
  }
}

extern "C" void kernel_launch(void* const* d_in, const int* in_sizes, int n_in,
                              void* d_out, int out_size, void* d_ws, size_t ws_size,
                              hipStream_t stream) {
  const float* x  = (const float*)d_in[0];   // [2,2048,1024]
  const float* Ww = (const float*)d_in[1];   // [3072,1024]
  const float* Wb = (const float*)d_in[2];   // [3072]
  const float* Ow = (const float*)d_in[3];   // [1024,1024]
  const float* Ob = (const float*)d_in[4];   // [1024]
  float* out = (float*)d_out;                // [2,2048,1024] fp32

  char* ws = (char*)d_ws;
  ushort* xb      = (ushort*)(ws);                              // 8 MB
  ushort* wqkvb   = (ushort*)(ws + (size_t)8  * 1024 * 1024);   // 6 MB
  ushort* outwb   = (ushort*)(ws + (size_t)14 * 1024 * 1024);   // 2 MB
  ushort* qkvb    = (ushort*)(ws + (size_t)16 * 1024 * 1024);   // 24 MB  [M][3072] bf16
  float*  mlocT   = (float*) (ws + (size_t)40 * 1024 * 1024);   // 8 MB
  ushort* statesT = (ushort*)(ws + (size_t)48 * 1024 * 1024);   // 4 MB
  ushort* yb      = (ushort*)(ws + (size_t)52 * 1024 * 1024);   // 8 MB   total 60 MB

  cvt_bf16<<<4096, 256, 0, stream>>>(x, xb, 1048576);
  cvt_bf16<<<3072, 256, 0, stream>>>(Ww, wqkvb, 786432);
  cvt_bf16<<<1024, 256, 0, stream>>>(Ow, outwb, 262144);
  gemm_bt<true, true><<<dim3(24, 32), 256, 0, stream>>>(xb, wqkvb, Wb, (void*)qkvb, 4096, 3072, 1024);
  kv_local<<<dim3(16, 32), 256, 0, stream>>>(qkvb, mlocT);
  kv_prefix<<<32, 256, 0, stream>>>(mlocT, statesT);
  attn_chunk<<<dim3(16, 32), 256, 0, stream>>>(qkvb, statesT, yb);
  gemm_bt<false, false><<<dim3(8, 32), 256, 0, stream>>>(yb, outwb, Ob, (void*)out, 4096, 1024, 1024);
}